// Round 1
// 2614.254 us; speedup vs baseline: 1.1506x; 1.1506x over previous
//
#include <hip/hip_runtime.h>
#include <stdint.h>

// ---------------------------------------------------------------------------
// LSTMSingle v3:
//  K0  zero h/c/tag buffers; Kcvt preconvert emb + W_ih to f16 in ws.
//  K1  x_proj GEMM (f16 MFMA, f16 operands).
//  K2  recurrence with TAGGED-WORD sync: each thread's h contribution is a
//      single u64 {2xf16 data | u32 tag=t+1} relaxed agent-scope store
//      (fire & forget; 8B stores are single-copy atomic). Readers spin on
//      tags of the words they consume -> no flag counter, no vmcnt(0) ack
//      stall, no separate poll round trip. Raw s_barrier + lgkmcnt(0) keeps
//      tagged loads/stores in flight across intra-phase barriers.
//  K3  final FC, HBM-bound on W_fc.
// ---------------------------------------------------------------------------

#define NB   128
#define LMAX 512
#define HD   512
#define G4   2048
#define NV   50000

// workspace layout (bytes)
#define H0C_OFF     0                            // compact final h [128][512] f16
#define T0_OFF      131072                       // tagged h parity0: 128*256*8
#define T1_OFF      393216                       // tagged h parity1
#define C_OFF       655360                       // c state f32 128*512*4
#define EMB16_OFF   917504
#define EMB16_BYTES (NV * HD * 2)                // 51,200,000
#define WIH16_OFF   (EMB16_OFF + EMB16_BYTES)
#define WIH16_BYTES (G4 * HD * 2)                // 2,097,152
#define XP_OFF      (WIH16_OFF + WIH16_BYTES)
#define INIT_W4     57344                        // 917504/16

typedef _Float16 f16;
typedef _Float16 half8  __attribute__((ext_vector_type(8)));
typedef float    float4v __attribute__((ext_vector_type(4)));
typedef uint32_t u32;
typedef unsigned long long u64;
typedef uint32_t u32x4 __attribute__((ext_vector_type(4)));

__device__ __forceinline__ half8 cvt8(const float* p) {
  float4v a = *(const float4v*)p;
  float4v b = *(const float4v*)(p + 4);
  half8 r;
  r[0] = (f16)a[0]; r[1] = (f16)a[1]; r[2] = (f16)a[2]; r[3] = (f16)a[3];
  r[4] = (f16)b[0]; r[5] = (f16)b[1]; r[6] = (f16)b[2]; r[7] = (f16)b[3];
  return r;
}
__device__ __forceinline__ float sigmoidf_(float x) { return 1.0f / (1.0f + __expf(-x)); }
__device__ __forceinline__ float tanhf_(float x)    { return 1.0f - 2.0f / (1.0f + __expf(2.0f * x)); }

// raw workgroup barrier: LDS visibility only, does NOT drain vmcnt
__device__ __forceinline__ void barx() {
  __builtin_amdgcn_sched_barrier(0);
  __builtin_amdgcn_s_waitcnt(0xC07F);   // lgkmcnt(0), vmcnt/expcnt untouched
  __builtin_amdgcn_s_barrier();
  __builtin_amdgcn_sched_barrier(0);
}

// ---------------------------------------------------------------- K0: init
extern "C" __global__ void k0_init(u32x4* ws4) {
  int idx = blockIdx.x * 256 + threadIdx.x;
  u32x4 z = {0u, 0u, 0u, 0u};
  if (idx < INIT_W4) ws4[idx] = z;
}

// ------------------------------------------------------------- Kcvt: f32->f16
extern "C" __global__ void __launch_bounds__(256)
k_cvt(const float* __restrict__ src, f16* __restrict__ dst, int n8) {
  int i = blockIdx.x * 256 + threadIdx.x;
  if (i >= n8) return;
  ((half8*)dst)[i] = cvt8(src + (size_t)i * 8);
}

// -------------------------------------------------------------- K1: x_proj
extern "C" __global__ void __launch_bounds__(256)
k1_xproj(const int* __restrict__ tokens, const int* __restrict__ lengths,
         const f16* __restrict__ emb16, const f16* __restrict__ wih16,
         const float* __restrict__ bih, const float* __restrict__ bhh,
         f16* __restrict__ xp, int t0c, int TC) {
  int b  = blockIdx.x;
  int mt = blockIdx.y;
  int nt = blockIdx.z;
  int len = lengths[b];
  int t0 = t0c + mt * 64;
  if (t0 >= len) return;

  __shared__ f16 As[64 * 512];                // 64 KB, XOR-swizzled granules
  int tid = threadIdx.x;

  #pragma unroll
  for (int it = 0; it < 16; ++it) {
    int gl = tid + 256 * it;
    int row = gl >> 6, gi = gl & 63;
    int tok = tokens[b * LMAX + t0 + row];
    half8 v = *(const half8*)(emb16 + (size_t)tok * HD + gi * 8);
    *(half8*)&As[row * 512 + ((gi ^ (row & 7)) * 8)] = v;
  }
  __syncthreads();

  int wave = tid >> 6, lane = tid & 63;
  int quad = lane >> 4, l15 = lane & 15;
  int col0 = nt * 128 + wave * 32;

  float4v acc[4][2] = {};
  for (int c = 0; c < 16; ++c) {
    half8 b0 = *(const half8*)(wih16 + (size_t)(col0 + l15) * HD + c * 32 + quad * 8);
    half8 b1 = *(const half8*)(wih16 + (size_t)(col0 + 16 + l15) * HD + c * 32 + quad * 8);
    #pragma unroll
    for (int mm = 0; mm < 4; ++mm) {
      int row = mm * 16 + l15;
      half8 a = *(const half8*)&As[row * 512 + (((c * 4 + quad) ^ (row & 7)) * 8)];
      acc[mm][0] = __builtin_amdgcn_mfma_f32_16x16x32_f16(a, b0, acc[mm][0], 0, 0, 0);
      acc[mm][1] = __builtin_amdgcn_mfma_f32_16x16x32_f16(a, b1, acc[mm][1], 0, 0, 0);
    }
  }

  #pragma unroll
  for (int q = 0; q < 2; ++q) {
    int gcol = col0 + q * 16 + l15;
    float bias = bih[gcol] + bhh[gcol];
    #pragma unroll
    for (int mm = 0; mm < 4; ++mm) {
      #pragma unroll
      for (int j = 0; j < 4; ++j) {
        int t = t0 + mm * 16 + quad * 4 + j;
        if (t < len)
          xp[((size_t)b * TC + (t - t0c)) * G4 + gcol] = (f16)(acc[mm][q][j] + bias);
      }
    }
  }
}

// ---------------------------------------------------------- K2: recurrence
// 64 wgs: pair p = wg&3 serves groups {2p, 2p+1}; memb m = wg>>2 owns
// h-columns [32m,32m+32). W_hh fragments register-resident (shared by both
// groups). h exchange: tagged u64 words through Infinity Cache; readers
// spin on tags (no flags, no store-ack stalls, no poll counter).
extern "C" __global__ void __launch_bounds__(256, 1)
k2_lstm(const int* __restrict__ lengths, const float* __restrict__ Whh,
        const f16* __restrict__ xp, u64* __restrict__ tb0, u64* __restrict__ tb1,
        f16* __restrict__ h0c, float* __restrict__ cbuf, int t0c, int TC) {
  int wg = blockIdx.x;
  int pair = wg & 3, memb = wg >> 2;
  int grpA = pair * 2, grpB = grpA + 1;
  int s0A = grpA * 16, s0B = grpB * 16;
  int tid = threadIdx.x;

  int gmA = 0, gmB = 0;
  for (int i = 0; i < 16; ++i) { int l = lengths[s0A + i]; gmA = l > gmA ? l : gmA; }
  for (int i = 0; i < 16; ++i) { int l = lengths[s0B + i]; gmB = l > gmB ? l : gmB; }
  int tendA = (t0c + TC < gmA) ? (t0c + TC) : gmA;
  int tendB = (t0c + TC < gmB) ? (t0c + TC) : gmB;
  int tmax = tendA > tendB ? tendA : tendB;
  if (t0c >= tmax) return;

  __shared__ f16 HsA[16 * 512], HsB[16 * 512];     // 32 KB
  __shared__ float gA[16][133], gB[16][133];       // padded: odd stride

  int wave = tid >> 6, lane = tid & 63;
  int quad = lane >> 4, l15 = lane & 15;

  // register-resident W_hh fragments: wave w <-> gate block w
  half8 wf0[16], wf1[16];
  {
    const float* r0 = Whh + (size_t)(wave * 512 + memb * 32 + l15) * HD;
    const float* r1 = r0 + (size_t)16 * HD;
    #pragma unroll
    for (int c = 0; c < 16; ++c) {
      wf0[c] = cvt8(r0 + c * 32 + quad * 8);
      wf1[c] = cvt8(r1 + c * 32 + quad * 8);
    }
  }

  // elementwise: thread owns (seq sE, 2 cols kk0..kk0+1) in each group
  int sE = tid >> 4, kE = tid & 15, kk0 = kE * 2;
  int lenA = lengths[s0A + sE], lenB = lengths[s0B + sE];
  float cA0 = cbuf[(size_t)(s0A + sE) * HD + memb * 32 + kk0];
  float cA1 = cbuf[(size_t)(s0A + sE) * HD + memb * 32 + kk0 + 1];
  float cB0 = cbuf[(size_t)(s0B + sE) * HD + memb * 32 + kk0];
  float cB1 = cbuf[(size_t)(s0B + sE) * HD + memb * 32 + kk0 + 1];

  // own tagged word indices + initial (frozen) h from previous chunk
  size_t wA = (size_t)(s0A + sE) * 256 + memb * 16 + kE;
  size_t wB = (size_t)(s0B + sE) * 256 + memb * 16 + kE;
  const u64* hin0 = (t0c & 1) ? tb1 : tb0;
  u32 hpA = (u32)hin0[wA];
  u32 hpB = (u32)hin0[wB];

  // staging address components: thread tid covers col-pair tid of every seq
  int gG = tid >> 2, w4 = (tid & 3) * 2;    // granule 0..63, f16 offset in granule

  u64 a[16], b[16];
  if (t0c < tendA) {
    #pragma unroll
    for (int r = 0; r < 16; ++r)
      a[r] = __hip_atomic_load(hin0 + (size_t)(s0A + r) * 256 + tid,
                               __ATOMIC_RELAXED, __HIP_MEMORY_SCOPE_AGENT);
  }

  for (int t = t0c; t < tmax; ++t) {
    bool actA = t < tendA, actB = t < tendB;
    const u64* tin = (t & 1) ? tb1 : tb0;
    u64*       tout = (t & 1) ? tb0 : tb1;
    u32 tg = (u32)t;

    // xp prefetch (unconditional within active group; in-bounds garbage ok)
    u32 xA[4], xB[4];
    if (actA) {
      const f16* p = xp + ((size_t)(s0A + sE) * TC + (t - t0c)) * G4 + memb * 32 + kk0;
      xA[0] = *(const u32*)p;          xA[1] = *(const u32*)(p + 512);
      xA[2] = *(const u32*)(p + 1024); xA[3] = *(const u32*)(p + 1536);
    }
    if (actB) {
      const f16* p = xp + ((size_t)(s0B + sE) * TC + (t - t0c)) * G4 + memb * 32 + kk0;
      xB[0] = *(const u32*)p;          xB[1] = *(const u32*)(p + 512);
      xB[2] = *(const u32*)(p + 1024); xB[3] = *(const u32*)(p + 1536);
    }

    // =================== phase A ===================
    if (actA) {
      // spin until all 16 tags == t (data+tag atomic in same u64)
      for (;;) {
        u32 bad = 0;
        #pragma unroll
        for (int r = 0; r < 16; ++r)
          bad |= ((u32)(a[r] >> 32) != tg) ? (1u << r) : 0u;
        if (!bad) break;
        __builtin_amdgcn_s_sleep(1);
        #pragma unroll
        for (int r = 0; r < 16; ++r)
          if (bad & (1u << r))
            a[r] = __hip_atomic_load(tin + (size_t)(s0A + r) * 256 + tid,
                                     __ATOMIC_RELAXED, __HIP_MEMORY_SCOPE_AGENT);
      }
      #pragma unroll
      for (int r = 0; r < 16; ++r)
        *(u32*)&HsA[r * 512 + ((gG ^ (r & 7)) << 3) + w4] = (u32)a[r];
      barx();
    }

    // issue B tagged loads early: latency hides under A's MFMA+elem
    if (actB) {
      #pragma unroll
      for (int r = 0; r < 16; ++r)
        b[r] = __hip_atomic_load(tin + (size_t)(s0B + r) * 256 + tid,
                                 __ATOMIC_RELAXED, __HIP_MEMORY_SCOPE_AGENT);
    }

    if (actA) {
      float4v a0e = {}, a0o = {}, a1e = {}, a1o = {};
      #pragma unroll
      for (int c = 0; c < 16; ++c) {
        half8 av = *(const half8*)&HsA[l15 * 512 + (((c * 4 + quad) ^ (l15 & 7)) * 8)];
        if (c & 1) {
          a0o = __builtin_amdgcn_mfma_f32_16x16x32_f16(av, wf0[c], a0o, 0, 0, 0);
          a1o = __builtin_amdgcn_mfma_f32_16x16x32_f16(av, wf1[c], a1o, 0, 0, 0);
        } else {
          a0e = __builtin_amdgcn_mfma_f32_16x16x32_f16(av, wf0[c], a0e, 0, 0, 0);
          a1e = __builtin_amdgcn_mfma_f32_16x16x32_f16(av, wf1[c], a1e, 0, 0, 0);
        }
      }
      float4v g0 = a0e + a0o, g1 = a1e + a1o;
      #pragma unroll
      for (int j = 0; j < 4; ++j) {
        gA[quad * 4 + j][wave * 32 + l15]      = g0[j];
        gA[quad * 4 + j][wave * 32 + 16 + l15] = g1[j];
      }
      barx();
      if (t < lenA) {
        union { u32 u; f16 h[2]; } xi, xf, xg, xo, hp;
        xi.u = xA[0]; xf.u = xA[1]; xg.u = xA[2]; xo.u = xA[3];
        float i0 = sigmoidf_(gA[sE][kk0]          + (float)xi.h[0]);
        float i1 = sigmoidf_(gA[sE][kk0 + 1]      + (float)xi.h[1]);
        float f0 = sigmoidf_(gA[sE][32 + kk0]     + (float)xf.h[0]);
        float f1 = sigmoidf_(gA[sE][32 + kk0 + 1] + (float)xf.h[1]);
        float q0 = tanhf_  (gA[sE][64 + kk0]      + (float)xg.h[0]);
        float q1 = tanhf_  (gA[sE][64 + kk0 + 1]  + (float)xg.h[1]);
        float o0 = sigmoidf_(gA[sE][96 + kk0]     + (float)xo.h[0]);
        float o1 = sigmoidf_(gA[sE][96 + kk0 + 1] + (float)xo.h[1]);
        cA0 = f0 * cA0 + i0 * q0;
        cA1 = f1 * cA1 + i1 * q1;
        hp.h[0] = (f16)(o0 * tanhf_(cA0));
        hp.h[1] = (f16)(o1 * tanhf_(cA1));
        hpA = hp.u;
      }
      u64 wv = ((u64)(u32)(t + 1) << 32) | (u64)hpA;
      __hip_atomic_store(tout + wA, wv, __ATOMIC_RELAXED, __HIP_MEMORY_SCOPE_AGENT);
    }

    // =================== phase B ===================
    if (actB) {
      for (;;) {
        u32 bad = 0;
        #pragma unroll
        for (int r = 0; r < 16; ++r)
          bad |= ((u32)(b[r] >> 32) != tg) ? (1u << r) : 0u;
        if (!bad) break;
        __builtin_amdgcn_s_sleep(1);
        #pragma unroll
        for (int r = 0; r < 16; ++r)
          if (bad & (1u << r))
            b[r] = __hip_atomic_load(tin + (size_t)(s0B + r) * 256 + tid,
                                     __ATOMIC_RELAXED, __HIP_MEMORY_SCOPE_AGENT);
      }
      #pragma unroll
      for (int r = 0; r < 16; ++r)
        *(u32*)&HsB[r * 512 + ((gG ^ (r & 7)) << 3) + w4] = (u32)b[r];
      // issue next-step A tagged loads: latency hides under B's MFMA+elem
      if (t + 1 < tendA) {
        #pragma unroll
        for (int r = 0; r < 16; ++r)
          a[r] = __hip_atomic_load(tout + (size_t)(s0A + r) * 256 + tid,
                                   __ATOMIC_RELAXED, __HIP_MEMORY_SCOPE_AGENT);
      }
      barx();
      float4v a0e = {}, a0o = {}, a1e = {}, a1o = {};
      #pragma unroll
      for (int c = 0; c < 16; ++c) {
        half8 av = *(const half8*)&HsB[l15 * 512 + (((c * 4 + quad) ^ (l15 & 7)) * 8)];
        if (c & 1) {
          a0o = __builtin_amdgcn_mfma_f32_16x16x32_f16(av, wf0[c], a0o, 0, 0, 0);
          a1o = __builtin_amdgcn_mfma_f32_16x16x32_f16(av, wf1[c], a1o, 0, 0, 0);
        } else {
          a0e = __builtin_amdgcn_mfma_f32_16x16x32_f16(av, wf0[c], a0e, 0, 0, 0);
          a1e = __builtin_amdgcn_mfma_f32_16x16x32_f16(av, wf1[c], a1e, 0, 0, 0);
        }
      }
      float4v g0 = a0e + a0o, g1 = a1e + a1o;
      #pragma unroll
      for (int j = 0; j < 4; ++j) {
        gB[quad * 4 + j][wave * 32 + l15]      = g0[j];
        gB[quad * 4 + j][wave * 32 + 16 + l15] = g1[j];
      }
      barx();
      if (t < lenB) {
        union { u32 u; f16 h[2]; } xi, xf, xg, xo, hp;
        xi.u = xB[0]; xf.u = xB[1]; xg.u = xB[2]; xo.u = xB[3];
        float i0 = sigmoidf_(gB[sE][kk0]          + (float)xi.h[0]);
        float i1 = sigmoidf_(gB[sE][kk0 + 1]      + (float)xi.h[1]);
        float f0 = sigmoidf_(gB[sE][32 + kk0]     + (float)xf.h[0]);
        float f1 = sigmoidf_(gB[sE][32 + kk0 + 1] + (float)xf.h[1]);
        float q0 = tanhf_  (gB[sE][64 + kk0]      + (float)xg.h[0]);
        float q1 = tanhf_  (gB[sE][64 + kk0 + 1]  + (float)xg.h[1]);
        float o0 = sigmoidf_(gB[sE][96 + kk0]     + (float)xo.h[0]);
        float o1 = sigmoidf_(gB[sE][96 + kk0 + 1] + (float)xo.h[1]);
        cB0 = f0 * cB0 + i0 * q0;
        cB1 = f1 * cB1 + i1 * q1;
        hp.h[0] = (f16)(o0 * tanhf_(cB0));
        hp.h[1] = (f16)(o1 * tanhf_(cB1));
        hpB = hp.u;
      }
      u64 wv = ((u64)(u32)(t + 1) << 32) | (u64)hpB;
      __hip_atomic_store(tout + wB, wv, __ATOMIC_RELAXED, __HIP_MEMORY_SCOPE_AGENT);
    } else if (t + 1 < tendA) {
      #pragma unroll
      for (int r = 0; r < 16; ++r)
        a[r] = __hip_atomic_load(tout + (size_t)(s0A + r) * 256 + tid,
                                 __ATOMIC_RELAXED, __HIP_MEMORY_SCOPE_AGENT);
    }
  }

  // persist cell state
  cbuf[(size_t)(s0A + sE) * HD + memb * 32 + kk0]     = cA0;
  cbuf[(size_t)(s0A + sE) * HD + memb * 32 + kk0 + 1] = cA1;
  cbuf[(size_t)(s0B + sE) * HD + memb * 32 + kk0]     = cB0;
  cbuf[(size_t)(s0B + sE) * HD + memb * 32 + kk0 + 1] = cB1;

  // compact final h for K3 (frozen values correct for finished seqs)
  *(u32*)&h0c[(size_t)(s0A + sE) * HD + memb * 32 + kk0] = hpA;
  *(u32*)&h0c[(size_t)(s0B + sE) * HD + memb * 32 + kk0] = hpB;
}

// ----------------------------------------------------------------- K3: FC
extern "C" __global__ void __launch_bounds__(256)
k3_fc(const f16* __restrict__ hT, const float* __restrict__ Wfc,
      const float* __restrict__ bfc, float* __restrict__ out) {
  int tid = threadIdx.x;
  int wave = tid >> 6, lane = tid & 63, quad = lane >> 4, l15 = lane & 15;
  int v = blockIdx.x * 64 + wave * 16 + l15;
  int vc = v < NV ? v : NV - 1;
  float4v acc[8] = {};
  for (int c = 0; c < 16; ++c) {
    half8 bfr = cvt8(Wfc + (size_t)vc * HD + c * 32 + quad * 8);
    #pragma unroll
    for (int mt = 0; mt < 8; ++mt) {
      half8 afr = *(const half8*)&hT[(size_t)(mt * 16 + l15) * HD + c * 32 + quad * 8];
      acc[mt] = __builtin_amdgcn_mfma_f32_16x16x32_f16(afr, bfr, acc[mt], 0, 0, 0);
    }
  }
  if (v < NV) {
    float bias = bfc[v];
    #pragma unroll
    for (int mt = 0; mt < 8; ++mt)
      #pragma unroll
      for (int j = 0; j < 4; ++j)
        out[(size_t)(mt * 16 + quad * 4 + j) * NV + v] = acc[mt][j] + bias;
  }
}

// ---------------------------------------------------------------- launcher
extern "C" void kernel_launch(void* const* d_in, const int* in_sizes, int n_in,
                              void* d_out, int out_size, void* d_ws, size_t ws_size,
                              hipStream_t stream) {
  (void)in_sizes; (void)n_in; (void)out_size;
  const int*   tokens  = (const int*)d_in[0];
  const int*   lengths = (const int*)d_in[1];
  const float* emb     = (const float*)d_in[2];
  const float* Wih     = (const float*)d_in[3];
  const float* Whh     = (const float*)d_in[4];
  const float* bih     = (const float*)d_in[5];
  const float* bhh     = (const float*)d_in[6];
  const float* Wfc     = (const float*)d_in[7];
  const float* bfc     = (const float*)d_in[8];
  float* out = (float*)d_out;
  char* ws = (char*)d_ws;

  f16*  h0c  = (f16*)(ws + H0C_OFF);
  u64*  tb0  = (u64*)(ws + T0_OFF);
  u64*  tb1  = (u64*)(ws + T1_OFF);
  float* cbuf = (float*)(ws + C_OFF);
  f16* emb16 = (f16*)(ws + EMB16_OFF);
  f16* wih16 = (f16*)(ws + WIH16_OFF);
  f16* xp    = (f16*)(ws + XP_OFF);

  int TC = 512;
  while (TC > 64 && (size_t)XP_OFF + (size_t)NB * TC * G4 * 2 > ws_size) TC >>= 1;

  hipLaunchKernelGGL(k0_init, dim3(224), dim3(256), 0, stream, (u32x4*)ws);
  hipLaunchKernelGGL(k_cvt, dim3((NV * HD / 8 + 255) / 256), dim3(256), 0, stream,
                     emb, emb16, NV * HD / 8);
  hipLaunchKernelGGL(k_cvt, dim3((G4 * HD / 8 + 255) / 256), dim3(256), 0, stream,
                     Wih, wih16, G4 * HD / 8);
  for (int t0 = 0; t0 < LMAX; t0 += TC) {
    hipLaunchKernelGGL(k1_xproj, dim3(NB, TC / 64, 16), dim3(256), 0, stream,
                       tokens, lengths, emb16, wih16, bih, bhh, xp, t0, TC);
    hipLaunchKernelGGL(k2_lstm, dim3(64), dim3(256), 0, stream,
                       lengths, Whh, xp, tb0, tb1, h0c, cbuf, t0, TC);
  }
  hipLaunchKernelGGL(k3_fc, dim3((NV + 63) / 64), dim3(256), 0, stream,
                     h0c, Wfc, bfc, out);
}

// Round 2
// 2164.166 us; speedup vs baseline: 1.3899x; 1.2080x over previous
//
#include <hip/hip_runtime.h>
#include <stdint.h>

// ---------------------------------------------------------------------------
// LSTMSingle v4:
//  K0  zero h/c/tag buffers; Kcvt preconvert emb + W_ih to f16 in ws.
//  K1  x_proj GEMM (f16 MFMA, f16 operands).
//  K2  recurrence, ONE GROUP PER WG (128 wgs): group g = seqs 16g..16g+16
//      served by 16 member wgs (memb owns h-cols 32m..32m+32, W_hh fragment
//      register-resident). h exchange via tagged u64 words {data|tag=t+1}
//      relaxed agent-scope atomics. One sync event per step (was 2 with the
//      paired A/B phases): spin -> stage -> MFMA -> elementwise -> store ->
//      prefetch. group = wg&7 co-locates a group's membs on one XCD under
//      round-robin dispatch (perf hint only).
//  K3  final FC, HBM-bound on W_fc.
// ---------------------------------------------------------------------------

#define NB   128
#define LMAX 512
#define HD   512
#define G4   2048
#define NV   50000

// workspace layout (bytes)
#define H0C_OFF     0                            // compact final h [128][512] f16
#define T0_OFF      131072                       // tagged h parity0: 128*256*8
#define T1_OFF      393216                       // tagged h parity1
#define C_OFF       655360                       // c state f32 128*512*4
#define EMB16_OFF   917504
#define EMB16_BYTES (NV * HD * 2)                // 51,200,000
#define WIH16_OFF   (EMB16_OFF + EMB16_BYTES)
#define WIH16_BYTES (G4 * HD * 2)                // 2,097,152
#define XP_OFF      (WIH16_OFF + WIH16_BYTES)
#define INIT_W4     57344                        // 917504/16

typedef _Float16 f16;
typedef _Float16 half8  __attribute__((ext_vector_type(8)));
typedef float    float4v __attribute__((ext_vector_type(4)));
typedef uint32_t u32;
typedef unsigned long long u64;
typedef uint32_t u32x4 __attribute__((ext_vector_type(4)));

__device__ __forceinline__ half8 cvt8(const float* p) {
  float4v a = *(const float4v*)p;
  float4v b = *(const float4v*)(p + 4);
  half8 r;
  r[0] = (f16)a[0]; r[1] = (f16)a[1]; r[2] = (f16)a[2]; r[3] = (f16)a[3];
  r[4] = (f16)b[0]; r[5] = (f16)b[1]; r[6] = (f16)b[2]; r[7] = (f16)b[3];
  return r;
}
__device__ __forceinline__ float sigmoidf_(float x) { return 1.0f / (1.0f + __expf(-x)); }
__device__ __forceinline__ float tanhf_(float x)    { return 1.0f - 2.0f / (1.0f + __expf(2.0f * x)); }

// raw workgroup barrier: LDS visibility only, does NOT drain vmcnt
__device__ __forceinline__ void barx() {
  __builtin_amdgcn_sched_barrier(0);
  __builtin_amdgcn_s_waitcnt(0xC07F);   // lgkmcnt(0), vmcnt/expcnt untouched
  __builtin_amdgcn_s_barrier();
  __builtin_amdgcn_sched_barrier(0);
}

// ---------------------------------------------------------------- K0: init
extern "C" __global__ void k0_init(u32x4* ws4) {
  int idx = blockIdx.x * 256 + threadIdx.x;
  u32x4 z = {0u, 0u, 0u, 0u};
  if (idx < INIT_W4) ws4[idx] = z;
}

// ------------------------------------------------------------- Kcvt: f32->f16
extern "C" __global__ void __launch_bounds__(256)
k_cvt(const float* __restrict__ src, f16* __restrict__ dst, int n8) {
  int i = blockIdx.x * 256 + threadIdx.x;
  if (i >= n8) return;
  ((half8*)dst)[i] = cvt8(src + (size_t)i * 8);
}

// -------------------------------------------------------------- K1: x_proj
extern "C" __global__ void __launch_bounds__(256)
k1_xproj(const int* __restrict__ tokens, const int* __restrict__ lengths,
         const f16* __restrict__ emb16, const f16* __restrict__ wih16,
         const float* __restrict__ bih, const float* __restrict__ bhh,
         f16* __restrict__ xp, int t0c, int TC) {
  int b  = blockIdx.x;
  int mt = blockIdx.y;
  int nt = blockIdx.z;
  int len = lengths[b];
  int t0 = t0c + mt * 64;
  if (t0 >= len) return;

  __shared__ f16 As[64 * 512];                // 64 KB, XOR-swizzled granules
  int tid = threadIdx.x;

  #pragma unroll
  for (int it = 0; it < 16; ++it) {
    int gl = tid + 256 * it;
    int row = gl >> 6, gi = gl & 63;
    int tok = tokens[b * LMAX + t0 + row];
    half8 v = *(const half8*)(emb16 + (size_t)tok * HD + gi * 8);
    *(half8*)&As[row * 512 + ((gi ^ (row & 7)) * 8)] = v;
  }
  __syncthreads();

  int wave = tid >> 6, lane = tid & 63;
  int quad = lane >> 4, l15 = lane & 15;
  int col0 = nt * 128 + wave * 32;

  float4v acc[4][2] = {};
  for (int c = 0; c < 16; ++c) {
    half8 b0 = *(const half8*)(wih16 + (size_t)(col0 + l15) * HD + c * 32 + quad * 8);
    half8 b1 = *(const half8*)(wih16 + (size_t)(col0 + 16 + l15) * HD + c * 32 + quad * 8);
    #pragma unroll
    for (int mm = 0; mm < 4; ++mm) {
      int row = mm * 16 + l15;
      half8 a = *(const half8*)&As[row * 512 + (((c * 4 + quad) ^ (row & 7)) * 8)];
      acc[mm][0] = __builtin_amdgcn_mfma_f32_16x16x32_f16(a, b0, acc[mm][0], 0, 0, 0);
      acc[mm][1] = __builtin_amdgcn_mfma_f32_16x16x32_f16(a, b1, acc[mm][1], 0, 0, 0);
    }
  }

  #pragma unroll
  for (int q = 0; q < 2; ++q) {
    int gcol = col0 + q * 16 + l15;
    float bias = bih[gcol] + bhh[gcol];
    #pragma unroll
    for (int mm = 0; mm < 4; ++mm) {
      #pragma unroll
      for (int j = 0; j < 4; ++j) {
        int t = t0 + mm * 16 + quad * 4 + j;
        if (t < len)
          xp[((size_t)b * TC + (t - t0c)) * G4 + gcol] = (f16)(acc[mm][q][j] + bias);
      }
    }
  }
}

// ---------------------------------------------------------- K2: recurrence
// 128 wgs: group g = wg&7 (16 seqs), memb m = wg>>3 owns h-cols [32m,32m+32).
// One phase per step. Tagged u64 words through IC; readers spin on tags.
extern "C" __global__ void __launch_bounds__(256, 1)
k2_lstm(const int* __restrict__ lengths, const float* __restrict__ Whh,
        const f16* __restrict__ xp, u64* __restrict__ tb0, u64* __restrict__ tb1,
        f16* __restrict__ h0c, float* __restrict__ cbuf, int t0c, int TC) {
  int wg = blockIdx.x;
  int grp = wg & 7, memb = wg >> 3;
  int s0 = grp * 16;
  int tid = threadIdx.x;

  int gm = 0;
  for (int i = 0; i < 16; ++i) { int l = lengths[s0 + i]; gm = l > gm ? l : gm; }
  int tend = (t0c + TC < gm) ? (t0c + TC) : gm;
  if (t0c >= tend) return;

  __shared__ f16 Hs[16 * 512];                 // 16 KB
  __shared__ float gS[16][133];                // padded: odd stride

  int wave = tid >> 6, lane = tid & 63;
  int quad = lane >> 4, l15 = lane & 15;

  // register-resident W_hh fragments: wave w <-> gate block w
  half8 wf0[16], wf1[16];
  {
    const float* r0 = Whh + (size_t)(wave * 512 + memb * 32 + l15) * HD;
    const float* r1 = r0 + (size_t)16 * HD;
    #pragma unroll
    for (int c = 0; c < 16; ++c) {
      wf0[c] = cvt8(r0 + c * 32 + quad * 8);
      wf1[c] = cvt8(r1 + c * 32 + quad * 8);
    }
  }

  // elementwise: thread owns (seq sE, 2 cols kk0..kk0+1)
  int sE = tid >> 4, kE = tid & 15, kk0 = kE * 2;
  int len = lengths[s0 + sE];
  float c0 = cbuf[(size_t)(s0 + sE) * HD + memb * 32 + kk0];
  float c1 = cbuf[(size_t)(s0 + sE) * HD + memb * 32 + kk0 + 1];

  // own tagged word + initial (frozen) h from previous chunk
  size_t wIdx = (size_t)(s0 + sE) * 256 + memb * 16 + kE;
  const u64* hin0 = (t0c & 1) ? tb1 : tb0;
  u32 hp = (u32)hin0[wIdx];

  // staging address components: thread tid covers col-pair tid of every seq
  int gG = tid >> 2, w4 = (tid & 3) * 2;       // granule 0..63, f16 offset

  u64 a[16];
  #pragma unroll
  for (int r = 0; r < 16; ++r)
    a[r] = __hip_atomic_load(hin0 + (size_t)(s0 + r) * 256 + tid,
                             __ATOMIC_RELAXED, __HIP_MEMORY_SCOPE_AGENT);

  for (int t = t0c; t < tend; ++t) {
    const u64* tin  = (t & 1) ? tb1 : tb0;
    u64*       tout = (t & 1) ? tb0 : tb1;
    u32 tg = (u32)t;

    // xp prefetch (covers the spin latency)
    u32 x4[4];
    {
      const f16* p = xp + ((size_t)(s0 + sE) * TC + (t - t0c)) * G4 + memb * 32 + kk0;
      x4[0] = *(const u32*)p;          x4[1] = *(const u32*)(p + 512);
      x4[2] = *(const u32*)(p + 1024); x4[3] = *(const u32*)(p + 1536);
    }

    // spin until all 16 tags == t (data+tag atomic in same u64)
    for (;;) {
      u32 bad = 0;
      #pragma unroll
      for (int r = 0; r < 16; ++r)
        bad |= ((u32)(a[r] >> 32) != tg) ? (1u << r) : 0u;
      if (!bad) break;
      __builtin_amdgcn_s_sleep(1);
      #pragma unroll
      for (int r = 0; r < 16; ++r)
        if (bad & (1u << r))
          a[r] = __hip_atomic_load(tin + (size_t)(s0 + r) * 256 + tid,
                                   __ATOMIC_RELAXED, __HIP_MEMORY_SCOPE_AGENT);
    }

    // stage h into LDS (XOR-swizzled granules)
    #pragma unroll
    for (int r = 0; r < 16; ++r)
      *(u32*)&Hs[r * 512 + ((gG ^ (r & 7)) << 3) + w4] = (u32)a[r];
    barx();

    // GEMM: gates = h @ Whh fragment
    float4v a0e = {}, a0o = {}, a1e = {}, a1o = {};
    #pragma unroll
    for (int c = 0; c < 16; ++c) {
      half8 av = *(const half8*)&Hs[l15 * 512 + (((c * 4 + quad) ^ (l15 & 7)) * 8)];
      if (c & 1) {
        a0o = __builtin_amdgcn_mfma_f32_16x16x32_f16(av, wf0[c], a0o, 0, 0, 0);
        a1o = __builtin_amdgcn_mfma_f32_16x16x32_f16(av, wf1[c], a1o, 0, 0, 0);
      } else {
        a0e = __builtin_amdgcn_mfma_f32_16x16x32_f16(av, wf0[c], a0e, 0, 0, 0);
        a1e = __builtin_amdgcn_mfma_f32_16x16x32_f16(av, wf1[c], a1e, 0, 0, 0);
      }
    }
    float4v g0 = a0e + a0o, g1 = a1e + a1o;
    #pragma unroll
    for (int j = 0; j < 4; ++j) {
      gS[quad * 4 + j][wave * 32 + l15]      = g0[j];
      gS[quad * 4 + j][wave * 32 + 16 + l15] = g1[j];
    }
    barx();

    // elementwise gate math (only while seq is active; frozen h re-stored)
    if (t < len) {
      union { u32 u; f16 h[2]; } xi, xf, xg, xo, hpk;
      xi.u = x4[0]; xf.u = x4[1]; xg.u = x4[2]; xo.u = x4[3];
      float i0 = sigmoidf_(gS[sE][kk0]          + (float)xi.h[0]);
      float i1 = sigmoidf_(gS[sE][kk0 + 1]      + (float)xi.h[1]);
      float f0 = sigmoidf_(gS[sE][32 + kk0]     + (float)xf.h[0]);
      float f1 = sigmoidf_(gS[sE][32 + kk0 + 1] + (float)xf.h[1]);
      float q0 = tanhf_  (gS[sE][64 + kk0]      + (float)xg.h[0]);
      float q1 = tanhf_  (gS[sE][64 + kk0 + 1]  + (float)xg.h[1]);
      float o0 = sigmoidf_(gS[sE][96 + kk0]     + (float)xo.h[0]);
      float o1 = sigmoidf_(gS[sE][96 + kk0 + 1] + (float)xo.h[1]);
      c0 = f0 * c0 + i0 * q0;
      c1 = f1 * c1 + i1 * q1;
      hpk.h[0] = (f16)(o0 * tanhf_(c0));
      hpk.h[1] = (f16)(o1 * tanhf_(c1));
      hp = hpk.u;
    }
    u64 wv = ((u64)(u32)(t + 1) << 32) | (u64)hp;
    __hip_atomic_store(tout + wIdx, wv, __ATOMIC_RELAXED, __HIP_MEMORY_SCOPE_AGENT);

    // prefetch next step's words immediately (validated by next spin)
    if (t + 1 < tend) {
      #pragma unroll
      for (int r = 0; r < 16; ++r)
        a[r] = __hip_atomic_load(tout + (size_t)(s0 + r) * 256 + tid,
                                 __ATOMIC_RELAXED, __HIP_MEMORY_SCOPE_AGENT);
    }
  }

  // persist cell state
  cbuf[(size_t)(s0 + sE) * HD + memb * 32 + kk0]     = c0;
  cbuf[(size_t)(s0 + sE) * HD + memb * 32 + kk0 + 1] = c1;

  // compact final h for K3 (frozen values correct for finished seqs)
  *(u32*)&h0c[(size_t)(s0 + sE) * HD + memb * 32 + kk0] = hp;
}

// ----------------------------------------------------------------- K3: FC
extern "C" __global__ void __launch_bounds__(256)
k3_fc(const f16* __restrict__ hT, const float* __restrict__ Wfc,
      const float* __restrict__ bfc, float* __restrict__ out) {
  int tid = threadIdx.x;
  int wave = tid >> 6, lane = tid & 63, quad = lane >> 4, l15 = lane & 15;
  int v = blockIdx.x * 64 + wave * 16 + l15;
  int vc = v < NV ? v : NV - 1;
  float4v acc[8] = {};
  for (int c = 0; c < 16; ++c) {
    half8 bfr = cvt8(Wfc + (size_t)vc * HD + c * 32 + quad * 8);
    #pragma unroll
    for (int mt = 0; mt < 8; ++mt) {
      half8 afr = *(const half8*)&hT[(size_t)(mt * 16 + l15) * HD + c * 32 + quad * 8];
      acc[mt] = __builtin_amdgcn_mfma_f32_16x16x32_f16(afr, bfr, acc[mt], 0, 0, 0);
    }
  }
  if (v < NV) {
    float bias = bfc[v];
    #pragma unroll
    for (int mt = 0; mt < 8; ++mt)
      #pragma unroll
      for (int j = 0; j < 4; ++j)
        out[(size_t)(mt * 16 + quad * 4 + j) * NV + v] = acc[mt][j] + bias;
  }
}

// ---------------------------------------------------------------- launcher
extern "C" void kernel_launch(void* const* d_in, const int* in_sizes, int n_in,
                              void* d_out, int out_size, void* d_ws, size_t ws_size,
                              hipStream_t stream) {
  (void)in_sizes; (void)n_in; (void)out_size;
  const int*   tokens  = (const int*)d_in[0];
  const int*   lengths = (const int*)d_in[1];
  const float* emb     = (const float*)d_in[2];
  const float* Wih     = (const float*)d_in[3];
  const float* Whh     = (const float*)d_in[4];
  const float* bih     = (const float*)d_in[5];
  const float* bhh     = (const float*)d_in[6];
  const float* Wfc     = (const float*)d_in[7];
  const float* bfc     = (const float*)d_in[8];
  float* out = (float*)d_out;
  char* ws = (char*)d_ws;

  f16*  h0c  = (f16*)(ws + H0C_OFF);
  u64*  tb0  = (u64*)(ws + T0_OFF);
  u64*  tb1  = (u64*)(ws + T1_OFF);
  float* cbuf = (float*)(ws + C_OFF);
  f16* emb16 = (f16*)(ws + EMB16_OFF);
  f16* wih16 = (f16*)(ws + WIH16_OFF);
  f16* xp    = (f16*)(ws + XP_OFF);

  int TC = 512;
  while (TC > 64 && (size_t)XP_OFF + (size_t)NB * TC * G4 * 2 > ws_size) TC >>= 1;

  hipLaunchKernelGGL(k0_init, dim3(224), dim3(256), 0, stream, (u32x4*)ws);
  hipLaunchKernelGGL(k_cvt, dim3((NV * HD / 8 + 255) / 256), dim3(256), 0, stream,
                     emb, emb16, NV * HD / 8);
  hipLaunchKernelGGL(k_cvt, dim3((G4 * HD / 8 + 255) / 256), dim3(256), 0, stream,
                     Wih, wih16, G4 * HD / 8);
  for (int t0 = 0; t0 < LMAX; t0 += TC) {
    hipLaunchKernelGGL(k1_xproj, dim3(NB, TC / 64, 16), dim3(256), 0, stream,
                       tokens, lengths, emb16, wih16, bih, bhh, xp, t0, TC);
    hipLaunchKernelGGL(k2_lstm, dim3(128), dim3(256), 0, stream,
                       lengths, Whh, xp, tb0, tb1, h0c, cbuf, t0, TC);
  }
  hipLaunchKernelGGL(k3_fc, dim3((NV + 63) / 64), dim3(256), 0, stream,
                     h0c, Wfc, bfc, out);
}